// Round 13
// baseline (216.879 us; speedup 1.0000x reference)
//
#include <hip/hip_runtime.h>

// ---------------------------------------------------------------------------
// SledAttention: x@Wqkv -> RoPE(q,k) -> softmax(qk^T*scale)v -> @Wout + b
// B=2 N=4096 C=512 H=8 d=64.
// Pipeline (4 kernels): prep -> gemm_qkv_rope -> flash_attn -> gemm_out_f16.
// R13: (a) combine_splits FUSED into gemm2's A-staging: A[row][h*64+d] =
//   (O0+O1)[bh][q][d] / (l0+l1)[bh][q] -- the 1/l factor lives on the K-dim
//   (per head), so it must be applied pre-MFMA; K-step ks == head ks makes
//   the Opart layout line up exactly. fp16 pk add/mul: err ~3e-5, negligible.
//   (b) gemm1 128x64 tiles: grid (24,64)=1536 blocks (was 768=3/CU,
//   grid-limited); wave owns 32 rows x 64 cols so RoPE partner dd^32 stays
//   in acc[mt][nt^2]; Q/K transpose tile reuses dead ldsA.
// R12 evidence: flash is NOT MFMA-bound (removing 17% MFMA work was
//   neutral); 3 pipes ~45% each, serial chain at 4 waves/SIMD. Parked.
// fp16 notes: projections single-pass fp16 MFMA (absmax 9.77e-4 at R11);
//   p = exp2(s) via RAW v_exp_f32 (R9: __builtin_exp2f = slow libm);
//   log2(e) folded into Q scale; flash (256,4) = VGPR 64 no-spill point.
// Workspace (55 MB):
//   [0,8M)    A2x fp16 [8192][512]      [8,11M)  B2qkv fp16 [1536][512]
//   [11,13M)  CSSN float2 cos/sin       [13,21M) Q fp16 [16][4096][64]
//   [21,29M)  K fp16                    [29,37M) V^T fp16 [16][64][4096]
//   [37,53M)  Opart fp16 [2][16][4096][64]   [53,53.5M) lpart fp32
//   [54,54.5M) B2out fp16 [512][512]
// ---------------------------------------------------------------------------

typedef float    floatx4 __attribute__((ext_vector_type(4)));
typedef _Float16 half8   __attribute__((ext_vector_type(8)));
typedef _Float16 half4   __attribute__((ext_vector_type(4)));

// raw v_exp_f32 (1 inst): D = 2^S0. NOT __builtin_exp2f (precise libm path).
__device__ __forceinline__ float fast_exp2(float x) {
#if __has_builtin(__builtin_amdgcn_exp2f)
  return __builtin_amdgcn_exp2f(x);
#else
  float r;
  asm("v_exp_f32 %0, %1" : "=v"(r) : "v"(x));
  return r;
#endif
}

// async global->LDS, 16B/lane; LDS dst = wave-uniform base + lane*16 (m104)
__device__ __forceinline__ void async16(const void* g, void* l) {
  __builtin_amdgcn_global_load_lds(
      (const __attribute__((address_space(1))) void*)g,
      (__attribute__((address_space(3))) void*)l, 16, 0, 0);
}

// ---------------- fused prep: cast_x | sincos | transpose(Wqkv,Wout) -------
__global__ __launch_bounds__(256) void prep(
    const float* __restrict__ X, const float* __restrict__ pos,
    const float* __restrict__ Wqkv, const float* __restrict__ Wout,
    _Float16* __restrict__ A2, float2* __restrict__ CSSN,
    _Float16* __restrict__ B2qkv, _Float16* __restrict__ B2out) {
  __shared__ float tile[64][65];
  const int bid = blockIdx.x, t = threadIdx.x;
  if (bid < 4096) {            // cast x: [M][512] fp32 -> fp16 (same layout)
    const int i = (bid * 256 + t) * 4;
    const float4 v = *(const float4*)(X + i);
    half4 h;
    h[0] = (_Float16)v.x; h[1] = (_Float16)v.y;
    h[2] = (_Float16)v.z; h[3] = (_Float16)v.w;
    *(half4*)(A2 + i) = h;
  } else if (bid < 5120) {     // cos/sin table
    const int i = (bid - 4096) * 256 + t;
    const float p = pos[i];
    CSSN[i] = make_float2(__cosf(p), __sinf(p));
  } else {                     // transpose W -> B2T [N][512] fp16
    const float* W; _Float16* B2T; int Ncols, bx, by;
    if (bid < 5312) { const int idx = bid - 5120; bx = idx % 24; by = idx / 24;
                      W = Wqkv; B2T = B2qkv; Ncols = 1536; }
    else            { const int idx = bid - 5312; bx = idx % 8;  by = idx / 8;
                      W = Wout; B2T = B2out; Ncols = 512; }
    const int k0 = by * 64, n0 = bx * 64;
    const int lane = t & 63, w = t >> 6;
#pragma unroll 4
    for (int i = 0; i < 16; ++i) {
      const int k = w * 16 + i;
      tile[k][lane] = W[(size_t)(k0 + k) * Ncols + n0 + lane];
    }
    __syncthreads();
#pragma unroll 4
    for (int i = 0; i < 16; ++i) {
      const int n = w * 16 + i;
      B2T[(size_t)(n0 + n) * 512 + k0 + lane] = (_Float16)tile[lane][n];
    }
  }
}

// ---------------- gemm1: fp16 MFMA + fused RoPE epilogue -------------------
// M=8192, N=1536 (q|k|v), K=512 (8 steps of BK=64). Grid (24,64): 128x64
// tile, 4 waves stacked in M (each 32 rows x full 64 cols -> RoPE partner
// dd^32 in-lane at acc[mt][nt^2]). kind = bx>>3, head = bx&7.
// Q/K epilogue: rope in regs -> wave-private transpose tile carved from
// dead ldsA -> half8 coalesced stores.
__global__ __launch_bounds__(256) void gemm_qkv_rope(
    const _Float16* __restrict__ A2, const _Float16* __restrict__ B2T,
    const float2* __restrict__ CSSN,
    _Float16* __restrict__ Qb, _Float16* __restrict__ Kb,
    _Float16* __restrict__ VT) {
  __shared__ __align__(16) _Float16 ldsA[128 * 64];
  __shared__ __align__(16) _Float16 ldsB[64 * 64];
  const int t = threadIdx.x, w = t >> 6, l = t & 63;
  const int lo = l & 15, hi = l >> 4, sw = lo & 7;
  const int m0 = blockIdx.y << 7, n0 = blockIdx.x << 6;

  const int strow = w * 8 + (l >> 3);
  const int schunk = (l & 7) ^ ((l >> 3) & 7);
  const _Float16* gA = A2 + (size_t)(m0 + strow) * 512 + schunk * 8;
  const _Float16* gB = B2T + (size_t)(n0 + strow) * 512 + schunk * 8;
  _Float16* lA = ldsA + w * 512 + l * 8;
  _Float16* lB = ldsB + w * 512 + l * 8;

  const int mw = w * 32;

  floatx4 acc[2][4];
#pragma unroll
  for (int mt = 0; mt < 2; ++mt)
#pragma unroll
    for (int nt = 0; nt < 4; ++nt) acc[mt][nt] = (floatx4){0.f, 0.f, 0.f, 0.f};

  for (int ks = 0; ks < 8; ++ks) {
    const int kk = ks * 64;
    __syncthreads();
#pragma unroll
    for (int i = 0; i < 4; ++i)
      async16(gA + (size_t)i * 32 * 512 + kk, lA + i * 2048);
#pragma unroll
    for (int i = 0; i < 2; ++i)
      async16(gB + (size_t)i * 32 * 512 + kk, lB + i * 2048);
    __syncthreads();  // drains vmcnt: tiles resident
#pragma unroll
    for (int kc = 0; kc < 2; ++kc) {
      const int slot = ((hi + 4 * kc) ^ sw) * 8;
      half8 af[2], bf[4];
#pragma unroll
      for (int mt = 0; mt < 2; ++mt)
        af[mt] = *(const half8*)(ldsA + (mw + mt * 16 + lo) * 64 + slot);
#pragma unroll
      for (int nt = 0; nt < 4; ++nt)
        bf[nt] = *(const half8*)(ldsB + (nt * 16 + lo) * 64 + slot);
#pragma unroll
      for (int mt = 0; mt < 2; ++mt)
#pragma unroll
        for (int nt = 0; nt < 4; ++nt)
          acc[mt][nt] = __builtin_amdgcn_mfma_f32_16x16x32_f16(
              af[mt], bf[nt], acc[mt][nt], 0, 0, 0);
    }
  }

  // ---- fused epilogue: col = bx*64 + nt*16 + lo; dd = nt*16+lo ----
  const int bx = blockIdx.x;
  const int kind = bx >> 3;                     // 0=q, 1=k, 2=v
  const int h = bx & 7;                         // head
  if (kind == 2) {
#pragma unroll
    for (int mt = 0; mt < 2; ++mt) {
      const int rowb = m0 + mw + mt * 16 + hi * 4;   // r=0 row; no b-crossing
      const int b = rowb >> 12, nn = rowb & 4095;
#pragma unroll
      for (int nt = 0; nt < 4; ++nt) {
        const int dd = nt * 16 + lo;
        half4 v4;
#pragma unroll
        for (int r = 0; r < 4; ++r) v4[r] = (_Float16)acc[mt][nt][r];
        *(half4*)(VT + ((size_t)((b * 8 + h) * 64 + dd)) * 4096 + nn) = v4;
      }
    }
  } else {
    _Float16* Db = kind ? Kb : Qb;
    const float sc = (kind == 0) ? 0.125f * 1.44269504f : 1.0f;  // log2e fold
    __syncthreads();   // kc-loop LDS reads done; reuse ldsA for transpose
    _Float16 (*qt_)[72] = (_Float16(*)[72])(ldsA + w * 2048);  // wave-private
#pragma unroll
    for (int mt = 0; mt < 2; ++mt) {
      // rope -> transpose tile [row=hi*4+r][col=nt*16+lo]
#pragma unroll
      for (int r = 0; r < 4; ++r) {
        const int row = m0 + mw + mt * 16 + hi * 4 + r;
        const int nn = row & 4095;
        const float2* cp = CSSN + (size_t)nn * 64 + lo;
#pragma unroll
        for (int nt = 0; nt < 4; ++nt) {
          const float2 cs = cp[nt * 16];
          const float x0 = acc[mt][nt][r];
          const float xp = acc[mt][nt ^ 2][r];          // partner dd^32
          const float rot = (nt & 2) ? xp : -xp;        // rotate_half sign
          qt_[hi * 4 + r][nt * 16 + lo] = (_Float16)((x0 * cs.x + rot * cs.y) * sc);
        }
      }
      // wave-lockstep readback: contiguous half8, coalesced 16B stores
#pragma unroll
      for (int pass = 0; pass < 2; ++pass) {
        const int rr = pass * 8 + (l >> 3);
        const int dcol = (l & 7) * 8;
        const half8 v = *(const half8*)&qt_[rr][dcol];
        const int row = m0 + mw + mt * 16 + rr;
        const int b = row >> 12, nn = row & 4095;
        *(half8*)(Db + ((size_t)((b * 8 + h) * 4096 + nn)) * 64 + dcol) = v;
      }
    }
  }
}

// ---------------- gemm2 (+fused combine): out = [(O0+O1)/l] @ Wout + b -----
// A[row=b*4096+q][k=h*64+d] = (O0+O1)[b*8+h][q][d] * (1/(l0+l1)[b*8+h][q]).
// K-step ks == head ks: Opart slice [sp][b*8+ks][q][0..63] is contiguous.
// Normalization applied during A-staging (per-head = per-K, can't be in
// epilogue). 128x64 tile, grid (8,64) = 512 blocks.
__global__ __launch_bounds__(256) void gemm_out_f16(
    const _Float16* __restrict__ Opart, const float* __restrict__ lpart,
    const _Float16* __restrict__ B2T, const float* __restrict__ bias,
    float* __restrict__ C) {
  __shared__ __align__(16) _Float16 ldsA[128 * 64];
  __shared__ __align__(16) _Float16 ldsB[64 * 64];
  const int t = threadIdx.x, w = t >> 6, l = t & 63;
  const int lo = l & 15, hi = l >> 4, sw = lo & 7;
  const int m0 = blockIdx.y << 7, n0 = blockIdx.x << 6;
  const int b = m0 >> 12, q0 = m0 & 4095;

  const int strow = w * 8 + (l >> 3);
  const int schunk = (l & 7) ^ ((l >> 3) & 7);
  const size_t aRow = (size_t)(q0 + strow) * 64 + schunk * 8;
  const _Float16* gA0 = Opart + ((size_t)(b * 8)) * 4096 * 64 + aRow;
  const _Float16* gA1 = Opart + ((size_t)(16 + b * 8)) * 4096 * 64 + aRow;
  const float* lp0 = lpart + (size_t)(b * 8) * 4096 + q0 + strow;
  const float* lp1 = lpart + (size_t)(16 + b * 8) * 4096 + q0 + strow;
  const _Float16* gB = B2T + (size_t)(n0 + strow) * 512 + schunk * 8;
  _Float16* lA = ldsA + w * 512 + l * 8;
  _Float16* lB = ldsB + w * 512 + l * 8;

  const int mw = (w >> 1) * 64, nw = (w & 1) * 32;

  floatx4 acc[4][2];
#pragma unroll
  for (int mt = 0; mt < 4; ++mt)
#pragma unroll
    for (int nt = 0; nt < 2; ++nt) acc[mt][nt] = (floatx4){0.f, 0.f, 0.f, 0.f};

  for (int ks = 0; ks < 8; ++ks) {
    const int kk = ks * 64;
    const size_t hoff = (size_t)ks * 4096 * 64;   // head-ks slice of Opart
    const int lhoff = ks * 4096;
    __syncthreads();
#pragma unroll
    for (int i = 0; i < 4; ++i) {   // A: load both splits, add, normalize
      const half8 o0 = *(const half8*)(gA0 + hoff + (size_t)i * 32 * 64);
      const half8 o1 = *(const half8*)(gA1 + hoff + (size_t)i * 32 * 64);
      const float ls = lp0[lhoff + i * 32] + lp1[lhoff + i * 32];
      const _Float16 inv = (_Float16)(1.f / ls);
      half8 s;
#pragma unroll
      for (int j = 0; j < 8; ++j) s[j] = (_Float16)((o0[j] + o1[j]) * inv);
      *(half8*)(lA + i * 2048) = s;
    }
#pragma unroll
    for (int i = 0; i < 2; ++i)
      async16(gB + (size_t)i * 32 * 512 + kk, lB + i * 2048);
    __syncthreads();
#pragma unroll
    for (int kc = 0; kc < 2; ++kc) {
      const int slot = ((hi + 4 * kc) ^ sw) * 8;
      half8 af[4], bf[2];
#pragma unroll
      for (int mt = 0; mt < 4; ++mt)
        af[mt] = *(const half8*)(ldsA + (mw + mt * 16 + lo) * 64 + slot);
#pragma unroll
      for (int nt = 0; nt < 2; ++nt)
        bf[nt] = *(const half8*)(ldsB + (nw + nt * 16 + lo) * 64 + slot);
#pragma unroll
      for (int mt = 0; mt < 4; ++mt)
#pragma unroll
        for (int nt = 0; nt < 2; ++nt)
          acc[mt][nt] = __builtin_amdgcn_mfma_f32_16x16x32_f16(
              af[mt], bf[nt], acc[mt][nt], 0, 0, 0);
    }
  }
#pragma unroll
  for (int mt = 0; mt < 4; ++mt)
#pragma unroll
    for (int r = 0; r < 4; ++r) {
      const int row = m0 + mw + mt * 16 + hi * 4 + r;
#pragma unroll
      for (int nt = 0; nt < 2; ++nt) {
        const int col = n0 + nw + nt * 16 + lo;
        C[(size_t)row * 512 + col] = acc[mt][nt][r] + bias[col];
      }
    }
}

// ---------------- MFMA flash attention, 2-way split-K over KV --------------
// Grid (32 qtiles, 16 bh, 2 splits) = 1024 blocks = 4/CU (register cap).
// f16 S^T = K Q^T; p = exp2(s) raw v_exp_f32; l via VALU adds.
__global__ __launch_bounds__(256, 4) void flash_attn(
    const _Float16* __restrict__ Qb, const _Float16* __restrict__ Kb,
    const _Float16* __restrict__ VT, _Float16* __restrict__ Opart,
    float* __restrict__ lpart) {
  __shared__ __align__(16) _Float16 ldsK[64 * 64];   // K[j][d], swizzled
  __shared__ __align__(16) _Float16 ldsV[64 * 64];   // V^T[d][j], swizzled
  const int t = threadIdx.x;
  const int w = t >> 6, l = t & 63;
  const int lo = l & 15, hi = l >> 4;
  const int sw = lo & 7;
  const int bh = blockIdx.y, qt = blockIdx.x, sp = blockIdx.z;

  const int srow = l >> 3;
  const int scol = (l & 7) ^ srow;
  const int goffK = srow * 64 + scol * 8;
  const size_t goffV = (size_t)srow * 4096 + scol * 8;
  const int ldst = l * 8;

  const _Float16* Qrow = Qb + ((size_t)bh * 4096 + qt * 128 + w * 32 + lo) * 64;
  half8 qf[2][2];
  qf[0][0] = *(const half8*)(Qrow + hi * 8);
  qf[0][1] = *(const half8*)(Qrow + hi * 8 + 32);
  qf[1][0] = *(const half8*)(Qrow + 16 * 64 + hi * 8);
  qf[1][1] = *(const half8*)(Qrow + 16 * 64 + hi * 8 + 32);

  floatx4 acc[2][4];
  float l_s[2] = {0.f, 0.f};   // lane-partial row sums (q=lo, j in hi-quad)
#pragma unroll
  for (int g = 0; g < 2; ++g)
#pragma unroll
    for (int dt = 0; dt < 4; ++dt) acc[g][dt] = (floatx4){0.f, 0.f, 0.f, 0.f};

  const _Float16* Kt = Kb + (size_t)bh * 4096 * 64;
  const _Float16* Vt = VT + (size_t)bh * 64 * 4096;

  for (int tt = sp * 32; tt < sp * 32 + 32; ++tt) {
    __syncthreads();
    {
      const _Float16* gK = Kt + (size_t)tt * 4096;
      const _Float16* gV = Vt + tt * 64;
      const int k0 = w * 2;
      async16(gK + (size_t)k0 * 512 + goffK,       ldsK + k0 * 512 + ldst);
      async16(gK + (size_t)(k0 + 1) * 512 + goffK, ldsK + (k0 + 1) * 512 + ldst);
      async16(gV + (size_t)k0 * 32768 + goffV,       ldsV + k0 * 512 + ldst);
      async16(gV + (size_t)(k0 + 1) * 32768 + goffV, ldsV + (k0 + 1) * 512 + ldst);
    }
    __syncthreads();

    floatx4 st[2][4];
#pragma unroll
    for (int jt = 0; jt < 4; ++jt) {
      const _Float16* kr = ldsK + (jt * 16 + lo) * 64;
      const half8 kf0 = *(const half8*)(kr + ((hi ^ sw) * 8));
      const half8 kf1 = *(const half8*)(kr + (((hi + 4) ^ sw) * 8));
#pragma unroll
      for (int g = 0; g < 2; ++g) {
        floatx4 z = (floatx4){0.f, 0.f, 0.f, 0.f};
        z = __builtin_amdgcn_mfma_f32_16x16x32_f16(kf0, qf[g][0], z, 0, 0, 0);
        z = __builtin_amdgcn_mfma_f32_16x16x32_f16(kf1, qf[g][1], z, 0, 0, 0);
        st[g][jt] = z;
      }
    }

    // p = exp2(s): 1 v_exp_f32 each; l in fp32 VALU; pack via cvt_pkrtz
    half4 pf[2][4];
#pragma unroll
    for (int g = 0; g < 2; ++g)
#pragma unroll
      for (int jt = 0; jt < 4; ++jt) {
        const float e0 = fast_exp2(st[g][jt][0]);
        const float e1 = fast_exp2(st[g][jt][1]);
        const float e2 = fast_exp2(st[g][jt][2]);
        const float e3 = fast_exp2(st[g][jt][3]);
        l_s[g] += (e0 + e1) + (e2 + e3);
        uint2 u;
        u.x = __builtin_bit_cast(unsigned, __builtin_amdgcn_cvt_pkrtz(e0, e1));
        u.y = __builtin_bit_cast(unsigned, __builtin_amdgcn_cvt_pkrtz(e2, e3));
        pf[g][jt] = __builtin_bit_cast(half4, u);
      }

#pragma unroll
    for (int dt = 0; dt < 4; ++dt) {
      half4 vf[4];
#pragma unroll
      for (int jt = 0; jt < 4; ++jt)
        vf[jt] = *(const half4*)(ldsV + (dt * 16 + lo) * 64 +
                                 (((jt * 2 + (hi >> 1)) ^ sw) * 8) + (hi & 1) * 4);
#pragma unroll
      for (int g = 0; g < 2; ++g)
#pragma unroll
        for (int jt = 0; jt < 4; ++jt)
          acc[g][dt] = __builtin_amdgcn_mfma_f32_16x16x16f16(
              pf[g][jt], vf[jt], acc[g][dt], 0, 0, 0);
    }
  }

  // epilogue: reduce l across hi-quads, store partials.
  _Float16* obase = Opart + ((size_t)(sp * 16 + bh)) * 4096 * 64;
  float*    lbase = lpart + ((size_t)(sp * 16 + bh)) * 4096;
#pragma unroll
  for (int g = 0; g < 2; ++g) {
    float v = l_s[g];
    v += __shfl_xor(v, 16);
    v += __shfl_xor(v, 32);
    if (hi == 0)
      lbase[qt * 128 + w * 32 + g * 16 + lo] = v;
#pragma unroll
    for (int r = 0; r < 4; ++r) {
      const int q = qt * 128 + w * 32 + g * 16 + hi * 4 + r;
#pragma unroll
      for (int dt = 0; dt < 4; ++dt)
        obase[(size_t)q * 64 + dt * 16 + lo] = (_Float16)acc[g][dt][r];
    }
  }
}

// ---------------------------------------------------------------------------
extern "C" void kernel_launch(void* const* d_in, const int* in_sizes, int n_in,
                              void* d_out, int out_size, void* d_ws, size_t ws_size,
                              hipStream_t stream) {
  const float* x     = (const float*)d_in[0];
  const float* pos   = (const float*)d_in[1];
  const float* w_qkv = (const float*)d_in[2];
  const float* w_out = (const float*)d_in[3];
  const float* b_out = (const float*)d_in[4];
  float* out = (float*)d_out;

  char* ws = (char*)d_ws;
  if (ws_size < (size_t)56 * 1024 * 1024) return;

  const size_t MB = 1024 * 1024;
  _Float16* A2x   = (_Float16*)ws;                     // [0,8M)
  _Float16* B2qkv = (_Float16*)(ws + 8 * MB);          // [8,11M)
  float2*   CSSN  = (float2*)(ws + 11 * MB);           // [11,13M)
  _Float16* Qb    = (_Float16*)(ws + 13 * MB);         // [13,21M)
  _Float16* Kb    = (_Float16*)(ws + 21 * MB);         // [21,29M)
  _Float16* VT    = (_Float16*)(ws + 29 * MB);         // [29,37M)
  _Float16* Opart = (_Float16*)(ws + 37 * MB);         // [37,53M)
  float*    lpart = (float*)(ws + 53 * MB);            // [53,53.5M)
  _Float16* B2out = (_Float16*)(ws + 54 * MB);         // [54,54.5M)

  prep<<<5376, 256, 0, stream>>>(x, pos, w_qkv, w_out, A2x, CSSN, B2qkv, B2out);
  gemm_qkv_rope<<<dim3(24, 64), 256, 0, stream>>>(A2x, B2qkv, CSSN, Qb, Kb, VT);
  flash_attn<<<dim3(32, 16, 2), 256, 0, stream>>>(Qb, Kb, VT, Opart, lpart);
  gemm_out_f16<<<dim3(8, 64), 256, 0, stream>>>(Opart, lpart, B2out, b_out, out);
}